// Round 2
// baseline (7670.158 us; speedup 1.0000x reference)
//
#include <hip/hip_runtime.h>
#include <hip/hip_bf16.h>

// Batched Viterbi decode (torchcrf CRF.decode), B=512, S=2048, T=48.
// Outputs: best_score f32[512], tags [512][2048] (f32 or i64 depending on harness).

#define BATCH 512
#define SEQ   2048
#define TT    48
#define BPLEN (SEQ - 1)      // 2047 backpointer rows
#define CHUNK 128
#define NCH   16             // ceil(2047/128)

// ---------------- Forward DP: one wave per batch, lane j = cur tag ----------
// Single-wave workgroup: no __syncthreads in the hot loop (same-wave DS ops
// retire in order; wave_barrier() is a free compiler fence; one
// s_waitcnt lgkmcnt(0) after the s[] write is RAW insurance). This keeps the
// emit-prefetch global load in flight across the whole step (no vmcnt drain).
__global__ __launch_bounds__(64) void vit_fwd(
    const float* __restrict__ feats, const float* __restrict__ startT,
    const float* __restrict__ endT, const float* __restrict__ trans,
    unsigned char* __restrict__ bp, int* __restrict__ last_tag,
    float* __restrict__ best_out)
{
    const int b = blockIdx.x;
    const int j = threadIdx.x;
    const bool act = j < TT;
    __shared__ __align__(16) float s[TT];
    __shared__ float fin[64];

    const float* fb = feats + (size_t)b * (SEQ * TT);

    // preload transition column trans[i][j] for i=0..47 into registers
    float tcol[TT];
#pragma unroll
    for (int i = 0; i < TT; ++i) tcol[i] = act ? trans[i * TT + j] : 0.f;

    if (act) s[j] = startT[j] + fb[j];   // init: start + emit[0]
    asm volatile("s_waitcnt lgkmcnt(0)" ::: "memory");
    __builtin_amdgcn_wave_barrier();

    float emit_next = act ? fb[TT + j] : 0.f;   // emit for t=1
    float snew = 0.f;                            // this lane's final score

    for (int t = 1; t < SEQ; ++t) {
        // broadcast-read all 48 prev scores (uniform addresses -> conflict-free)
        float sv[TT];
#pragma unroll
        for (int q = 0; q < TT / 4; ++q) {
            float4 vv = reinterpret_cast<const float4*>(s)[q];
            sv[4 * q + 0] = vv.x; sv[4 * q + 1] = vv.y;
            sv[4 * q + 2] = vv.z; sv[4 * q + 3] = vv.w;
        }
        float emit = emit_next;
        int tn = (t + 1 < SEQ) ? (t + 1) : (SEQ - 1);
        emit_next = act ? fb[(size_t)tn * TT + j] : 0.f;  // prefetch next emit

        // argmax_i( sv[i] + tcol[i] ) via contiguous-pair tree.
        // Keep-left on ties at every level == global first-occurrence argmax.
        float v[24]; int ix[24];
#pragma unroll
        for (int k = 0; k < 24; ++k) {
            float a = sv[2 * k]     + tcol[2 * k];
            float c = sv[2 * k + 1] + tcol[2 * k + 1];
            bool g = c > a;
            v[k]  = g ? c : a;
            ix[k] = g ? (2 * k + 1) : (2 * k);
        }
#pragma unroll
        for (int k = 0; k < 12; ++k) {
            bool g = v[2 * k + 1] > v[2 * k];
            v[k]  = g ? v[2 * k + 1]  : v[2 * k];
            ix[k] = g ? ix[2 * k + 1] : ix[2 * k];
        }
#pragma unroll
        for (int k = 0; k < 6; ++k) {
            bool g = v[2 * k + 1] > v[2 * k];
            v[k]  = g ? v[2 * k + 1]  : v[2 * k];
            ix[k] = g ? ix[2 * k + 1] : ix[2 * k];
        }
#pragma unroll
        for (int k = 0; k < 3; ++k) {
            bool g = v[2 * k + 1] > v[2 * k];
            v[k]  = g ? v[2 * k + 1]  : v[2 * k];
            ix[k] = g ? ix[2 * k + 1] : ix[2 * k];
        }
        bool g1 = v[1] > v[0];
        float bv = g1 ? v[1] : v[0];
        int   bi = g1 ? ix[1] : ix[0];
        bool g2 = v[2] > bv;
        bv = g2 ? v[2] : bv;
        bi = g2 ? ix[2] : bi;

        if (act) bp[((size_t)(t - 1) * BATCH + b) * TT + j] = (unsigned char)bi;

        snew = bv + emit;
        __builtin_amdgcn_wave_barrier();   // don't sink the write above the reads
        if (act) s[j] = snew;
        asm volatile("s_waitcnt lgkmcnt(0)" ::: "memory");  // RAW for next read
        __builtin_amdgcn_wave_barrier();
    }

    // final: + end_transitions, argmax over tags (first occurrence)
    fin[threadIdx.x] = act ? (snew + endT[j]) : -1e30f;
    __syncthreads();   // once; cost irrelevant
    if (threadIdx.x == 0) {
        float bb = fin[0]; int bt = 0;
        for (int i = 1; i < TT; ++i)
            if (fin[i] > bb) { bb = fin[i]; bt = i; }
        best_out[b] = bb;
        last_tag[b] = bt;
    }
}

// ------------- Backtrack phase 1: compose per-chunk pointer maps ------------
__global__ __launch_bounds__(64) void vit_compose(
    const unsigned char* __restrict__ bp, unsigned char* __restrict__ maps)
{
    const int b = blockIdx.x, c = blockIdx.y;
    const int k_lo = c * CHUNK;
    const int len = min(CHUNK, BPLEN - k_lo);
    __shared__ __align__(16) unsigned char rows[CHUNK * TT];  // 6 KiB
    unsigned int* rows32 = reinterpret_cast<unsigned int*>(rows);

    const int ndw = len * (TT / 4);      // 12 dwords per 48B row
    for (int f = threadIdx.x; f < ndw; f += 64) {
        int row = f / 12, dwi = f % 12;
        const unsigned int* src = reinterpret_cast<const unsigned int*>(
            bp + ((size_t)(k_lo + row) * BATCH + b) * TT);
        rows32[row * 12 + dwi] = src[dwi];
    }
    __syncthreads();

    int j = threadIdx.x;
    if (j < TT) {
        int cur = j;                     // hypothesis: tag at chunk end == j
        for (int t = len - 1; t >= 0; --t) cur = rows[t * TT + cur];
        maps[((size_t)b * NCH + c) * TT + j] = (unsigned char)cur;
    }
}

// ------------- Backtrack phase 2: boundary tags via 16 chunk maps -----------
__global__ void vit_boundary(
    const unsigned char* __restrict__ maps, const int* __restrict__ last_tag,
    unsigned char* __restrict__ btag, void* __restrict__ out_tags, int i64mode)
{
    int b = threadIdx.x;                 // launched with 512 threads, 1 block
    if (b >= BATCH) return;
    int cur = last_tag[b];
    if (i64mode) ((long long*)out_tags)[(size_t)b * SEQ + (SEQ - 1)] = cur;
    else         ((float*)out_tags)[(size_t)b * SEQ + (SEQ - 1)] = (float)cur;
    for (int c = NCH - 1; c >= 0; --c) {
        btag[b * NCH + c] = (unsigned char)cur;     // tag at chunk c's end
        cur = maps[((size_t)b * NCH + c) * TT + cur];
    }
}

// ------------- Backtrack phase 3: emit tags within each chunk ---------------
__global__ __launch_bounds__(64) void vit_emit(
    const unsigned char* __restrict__ bp, const unsigned char* __restrict__ btag,
    void* __restrict__ out_tags, int i64mode)
{
    const int b = blockIdx.x, c = blockIdx.y;
    const int k_lo = c * CHUNK;
    const int len = min(CHUNK, BPLEN - k_lo);
    __shared__ __align__(16) unsigned char rows[CHUNK * TT];
    __shared__ unsigned char path[CHUNK];
    unsigned int* rows32 = reinterpret_cast<unsigned int*>(rows);

    const int ndw = len * (TT / 4);
    for (int f = threadIdx.x; f < ndw; f += 64) {
        int row = f / 12, dwi = f % 12;
        const unsigned int* src = reinterpret_cast<const unsigned int*>(
            bp + ((size_t)(k_lo + row) * BATCH + b) * TT);
        rows32[row * 12 + dwi] = src[dwi];
    }
    __syncthreads();

    if (threadIdx.x == 0) {
        int cur = btag[b * NCH + c];     // tag at position k_lo + len
        for (int t = len - 1; t >= 0; --t) {
            cur = rows[t * TT + cur];
            path[t] = (unsigned char)cur;   // tag at position k_lo + t
        }
    }
    __syncthreads();

    for (int k = threadIdx.x; k < len; k += 64) {
        int tag = path[k];
        if (i64mode) ((long long*)out_tags)[(size_t)b * SEQ + k_lo + k] = tag;
        else         ((float*)out_tags)[(size_t)b * SEQ + k_lo + k] = (float)tag;
    }
}

extern "C" void kernel_launch(void* const* d_in, const int* in_sizes, int n_in,
                              void* d_out, int out_size, void* d_ws, size_t ws_size,
                              hipStream_t stream) {
    const float* feats  = (const float*)d_in[0];
    const float* startT = (const float*)d_in[1];
    const float* endT   = (const float*)d_in[2];
    const float* trans  = (const float*)d_in[3];

    // workspace layout (bytes)
    unsigned char* ws   = (unsigned char*)d_ws;
    unsigned char* bp   = ws;                                 // 2047*512*48 = 50,307,072
    unsigned char* maps = ws + (size_t)BPLEN * BATCH * TT;    // 512*16*48 = 393,216
    unsigned char* btag = maps + (size_t)BATCH * NCH * TT;    // 512*16 = 8,192
    int* last_tag       = (int*)(btag + (size_t)BATCH * NCH); // 512*4

    float* best_out = (float*)d_out;
    void* out_tags  = (void*)((float*)d_out + BATCH);  // after 512 score floats
    const int i64mode = (out_size == BATCH + 2 * BATCH * SEQ) ? 1 : 0;

    vit_fwd<<<BATCH, 64, 0, stream>>>(feats, startT, endT, trans,
                                      bp, last_tag, best_out);
    vit_compose<<<dim3(BATCH, NCH), 64, 0, stream>>>(bp, maps);
    vit_boundary<<<1, BATCH, 0, stream>>>(maps, last_tag, btag, out_tags, i64mode);
    vit_emit<<<dim3(BATCH, NCH), 64, 0, stream>>>(bp, btag, out_tags, i64mode);
}

// Round 5
// 7480.915 us; speedup vs baseline: 1.0253x; 1.0253x over previous
//
#include <hip/hip_runtime.h>
#include <hip/hip_bf16.h>

// Batched Viterbi decode (torchcrf CRF.decode), B=512, S=2048, T=48.
// Outputs: best_score f32[512], tags [512][2048] (f32 or i64 depending on harness).

#define BATCH 512
#define SEQ   2048
#define TT    48
#define BPLEN (SEQ - 1)      // 2047 backpointer rows
#define CHUNK 128
#define NCH   16             // ceil(2047/128)

// ---------------- Forward DP: one wave per batch, lane j = cur tag ----------
// __launch_bounds__(64, 1): ONE wave per EU minimum -> full 512-VGPR budget.
// (Round-2 post-mortem: without it the allocator targeted 56 VGPRs and
// spilled tcol[48]+tree temps to scratch -> 8700 cy/step.)
// Single-wave workgroup: no __syncthreads in the hot loop; same-wave DS ops
// retire in order; wave_barrier() fences compiler reordering; one explicit
// s_waitcnt lgkmcnt(0) after the s[] write is RAW insurance.
__global__ __launch_bounds__(64, 1) void vit_fwd(
    const float* __restrict__ feats, const float* __restrict__ startT,
    const float* __restrict__ endT, const float* __restrict__ trans,
    unsigned char* __restrict__ bp, int* __restrict__ last_tag,
    float* __restrict__ best_out)
{
    const int b = blockIdx.x;
    const int j = threadIdx.x;
    const int jj = j < TT ? j : TT - 1;      // clamped lane for loads
    const bool act = j < TT;
    __shared__ __align__(16) float s[TT];
    __shared__ float fin[64];

    const float* fb = feats + (size_t)b * (SEQ * TT);

    // preload transition column trans[i][jj] for i=0..47 into registers
    float tcol[TT];
#pragma unroll
    for (int i = 0; i < TT; ++i) tcol[i] = trans[i * TT + jj];

    if (act) s[j] = startT[j] + fb[j];   // init: start + emit[0]
    asm volatile("s_waitcnt lgkmcnt(0)" ::: "memory");
    __builtin_amdgcn_wave_barrier();

    // emit prefetch pipeline, depth 2 (covers ~900cy HBM latency at ~450cy/step)
    float emit_c = fb[(size_t)1 * TT + jj];   // for t=1
    float emit_n = fb[(size_t)2 * TT + jj];   // for t=2
    float snew = 0.f;

    for (int t = 1; t < SEQ; ++t) {
        float emit = emit_c;
        int tp = t + 2 < SEQ ? t + 2 : SEQ - 1;
        float emit_f = fb[(size_t)tp * TT + jj];   // prefetch t+2

        // argmax_i( s[i] + tcol[i] ), fused LDS-read + contiguous-pair tree.
        // Keep-left on ties at every level == first-occurrence argmax.
        float v[24]; int ix[24];
#pragma unroll
        for (int q = 0; q < TT / 4; ++q) {          // 12 float4 broadcast reads
            float4 vv = reinterpret_cast<const float4*>(s)[q];
            float c0 = vv.x + tcol[4 * q + 0];
            float c1 = vv.y + tcol[4 * q + 1];
            float c2 = vv.z + tcol[4 * q + 2];
            float c3 = vv.w + tcol[4 * q + 3];
            bool gA = c1 > c0;
            v[2 * q + 0]  = gA ? c1 : c0;
            ix[2 * q + 0] = gA ? (4 * q + 1) : (4 * q + 0);
            bool gB = c3 > c2;
            v[2 * q + 1]  = gB ? c3 : c2;
            ix[2 * q + 1] = gB ? (4 * q + 3) : (4 * q + 2);
        }
#pragma unroll
        for (int k = 0; k < 12; ++k) {
            bool g = v[2 * k + 1] > v[2 * k];
            v[k]  = g ? v[2 * k + 1]  : v[2 * k];
            ix[k] = g ? ix[2 * k + 1] : ix[2 * k];
        }
#pragma unroll
        for (int k = 0; k < 6; ++k) {
            bool g = v[2 * k + 1] > v[2 * k];
            v[k]  = g ? v[2 * k + 1]  : v[2 * k];
            ix[k] = g ? ix[2 * k + 1] : ix[2 * k];
        }
#pragma unroll
        for (int k = 0; k < 3; ++k) {
            bool g = v[2 * k + 1] > v[2 * k];
            v[k]  = g ? v[2 * k + 1]  : v[2 * k];
            ix[k] = g ? ix[2 * k + 1] : ix[2 * k];
        }
        bool g1 = v[1] > v[0];
        float bv = g1 ? v[1] : v[0];
        int   bi = g1 ? ix[1] : ix[0];
        bool g2 = v[2] > bv;
        bv = g2 ? v[2] : bv;
        bi = g2 ? ix[2] : bi;

        if (act) bp[((size_t)(t - 1) * BATCH + b) * TT + j] = (unsigned char)bi;

        snew = bv + emit;
        emit_c = emit_n;            // rotate prefetch pipeline
        emit_n = emit_f;
        __builtin_amdgcn_wave_barrier();   // don't sink the write above the reads
        if (act) s[j] = snew;
        asm volatile("s_waitcnt lgkmcnt(0)" ::: "memory");  // RAW for next read
        __builtin_amdgcn_wave_barrier();
    }

    // final: + end_transitions, argmax over tags (first occurrence)
    fin[threadIdx.x] = act ? (snew + endT[j]) : -1e30f;
    __syncthreads();   // once; cost irrelevant
    if (threadIdx.x == 0) {
        float bb = fin[0]; int bt = 0;
        for (int i = 1; i < TT; ++i)
            if (fin[i] > bb) { bb = fin[i]; bt = i; }
        best_out[b] = bb;
        last_tag[b] = bt;
    }
}

// ------------- Backtrack phase 1: compose per-chunk pointer maps ------------
__global__ __launch_bounds__(64) void vit_compose(
    const unsigned char* __restrict__ bp, unsigned char* __restrict__ maps)
{
    const int b = blockIdx.x, c = blockIdx.y;
    const int k_lo = c * CHUNK;
    const int len = min(CHUNK, BPLEN - k_lo);
    __shared__ __align__(16) unsigned char rows[CHUNK * TT];  // 6 KiB
    unsigned int* rows32 = reinterpret_cast<unsigned int*>(rows);

    const int ndw = len * (TT / 4);      // 12 dwords per 48B row
    for (int f = threadIdx.x; f < ndw; f += 64) {
        int row = f / 12, dwi = f % 12;
        const unsigned int* src = reinterpret_cast<const unsigned int*>(
            bp + ((size_t)(k_lo + row) * BATCH + b) * TT);
        rows32[row * 12 + dwi] = src[dwi];
    }
    __syncthreads();

    int j = threadIdx.x;
    if (j < TT) {
        int cur = j;                     // hypothesis: tag at chunk end == j
        for (int t = len - 1; t >= 0; --t) cur = rows[t * TT + cur];
        maps[((size_t)b * NCH + c) * TT + j] = (unsigned char)cur;
    }
}

// ------------- Backtrack phase 2: boundary tags via 16 chunk maps -----------
__global__ void vit_boundary(
    const unsigned char* __restrict__ maps, const int* __restrict__ last_tag,
    unsigned char* __restrict__ btag, void* __restrict__ out_tags, int i64mode)
{
    int b = threadIdx.x;                 // launched with 512 threads, 1 block
    if (b >= BATCH) return;
    int cur = last_tag[b];
    if (i64mode) ((long long*)out_tags)[(size_t)b * SEQ + (SEQ - 1)] = cur;
    else         ((float*)out_tags)[(size_t)b * SEQ + (SEQ - 1)] = (float)cur;
    for (int c = NCH - 1; c >= 0; --c) {
        btag[b * NCH + c] = (unsigned char)cur;     // tag at chunk c's end
        cur = maps[((size_t)b * NCH + c) * TT + cur];
    }
}

// ------------- Backtrack phase 3: emit tags within each chunk ---------------
__global__ __launch_bounds__(64) void vit_emit(
    const unsigned char* __restrict__ bp, const unsigned char* __restrict__ btag,
    void* __restrict__ out_tags, int i64mode)
{
    const int b = blockIdx.x, c = blockIdx.y;
    const int k_lo = c * CHUNK;
    const int len = min(CHUNK, BPLEN - k_lo);
    __shared__ __align__(16) unsigned char rows[CHUNK * TT];
    __shared__ unsigned char path[CHUNK];
    unsigned int* rows32 = reinterpret_cast<unsigned int*>(rows);

    const int ndw = len * (TT / 4);
    for (int f = threadIdx.x; f < ndw; f += 64) {
        int row = f / 12, dwi = f % 12;
        const unsigned int* src = reinterpret_cast<const unsigned int*>(
            bp + ((size_t)(k_lo + row) * BATCH + b) * TT);
        rows32[row * 12 + dwi] = src[dwi];
    }
    __syncthreads();

    if (threadIdx.x == 0) {
        int cur = btag[b * NCH + c];     // tag at position k_lo + len
        for (int t = len - 1; t >= 0; --t) {
            cur = rows[t * TT + cur];
            path[t] = (unsigned char)cur;   // tag at position k_lo + t
        }
    }
    __syncthreads();

    for (int k = threadIdx.x; k < len; k += 64) {
        int tag = path[k];
        if (i64mode) ((long long*)out_tags)[(size_t)b * SEQ + k_lo + k] = tag;
        else         ((float*)out_tags)[(size_t)b * SEQ + k_lo + k] = (float)tag;
    }
}

extern "C" void kernel_launch(void* const* d_in, const int* in_sizes, int n_in,
                              void* d_out, int out_size, void* d_ws, size_t ws_size,
                              hipStream_t stream) {
    const float* feats  = (const float*)d_in[0];
    const float* startT = (const float*)d_in[1];
    const float* endT   = (const float*)d_in[2];
    const float* trans  = (const float*)d_in[3];

    // workspace layout (bytes)
    unsigned char* ws   = (unsigned char*)d_ws;
    unsigned char* bp   = ws;                                 // 2047*512*48 = 50,307,072
    unsigned char* maps = ws + (size_t)BPLEN * BATCH * TT;    // 512*16*48 = 393,216
    unsigned char* btag = maps + (size_t)BATCH * NCH * TT;    // 512*16 = 8,192
    int* last_tag       = (int*)(btag + (size_t)BATCH * NCH); // 512*4

    float* best_out = (float*)d_out;
    void* out_tags  = (void*)((float*)d_out + BATCH);  // after 512 score floats
    const int i64mode = (out_size == BATCH + 2 * BATCH * SEQ) ? 1 : 0;

    vit_fwd<<<BATCH, 64, 0, stream>>>(feats, startT, endT, trans,
                                      bp, last_tag, best_out);
    vit_compose<<<dim3(BATCH, NCH), 64, 0, stream>>>(bp, maps);
    vit_boundary<<<1, BATCH, 0, stream>>>(maps, last_tag, btag, out_tags, i64mode);
    vit_emit<<<dim3(BATCH, NCH), 64, 0, stream>>>(bp, btag, out_tags, i64mode);
}

// Round 7
// 1900.691 us; speedup vs baseline: 4.0355x; 3.9359x over previous
//
#include <hip/hip_runtime.h>
#include <hip/hip_bf16.h>

// Batched Viterbi decode (torchcrf CRF.decode), B=512, S=2048, T=48.
// Outputs: best_score f32[512], tags [512][2048] (f32 or i64 depending on harness).
//
// R5 post-mortem: VGPR=44 with tcol[48] in source => per-lane arrays were in
// SCRATCH, tree ran with memory round-trips on the serial compare chain
// (~8500 cy/step, ~5-10x source VALU count). This version has ZERO indexable
// per-lane arrays in the hot loop: every value is a named scalar (macro-
// generated), so scratch allocation is impossible.

#define BATCH 512
#define SEQ   2048
#define TT    48
#define BPLEN (SEQ - 1)      // 2047 backpointer rows
#define CHUNK 128
#define NCH   16             // ceil(2047/128)

// combine (va,xa),(vb,xb) -> (vc,xc), keep-left on ties (first-occurrence argmax)
#define CMB(vc, xc, va, xa, vb, xb) \
    const bool g_##vc = (vb) > (va); \
    const float vc = g_##vc ? (vb) : (va); \
    const int xc = g_##vc ? (xb) : (xa);

// level-0 pair from LDS quad sq, fields f0/f1, tag indices e0<e1
#define P0(k, sq, f0, f1, e0, e1) \
    const float a_##k = sq.f0 + tc##e0; \
    const float b_##k = sq.f1 + tc##e1; \
    const bool g0_##k = b_##k > a_##k; \
    const float v##k = g0_##k ? b_##k : a_##k; \
    const int x##k = g0_##k ? e1 : e0;

#define LT(i) const float tc##i = trans[i * TT + jj];

// ---------------- Forward DP: one wave per batch, lane j = cur tag ----------
__global__ __launch_bounds__(64, 1) void vit_fwd(
    const float* __restrict__ feats, const float* __restrict__ startT,
    const float* __restrict__ endT, const float* __restrict__ trans,
    unsigned char* __restrict__ bp, int* __restrict__ last_tag,
    float* __restrict__ best_out)
{
    const int b = blockIdx.x;
    const int j = threadIdx.x;
    const int jj = j < TT ? j : TT - 1;      // clamped lane for loads
    const bool act = j < TT;
    __shared__ __align__(16) float s[TT];
    __shared__ float fin[64];
    const float4* ls = reinterpret_cast<const float4*>(s);

    const float* fb = feats + (size_t)b * (SEQ * TT);

    // 48 named transition-column scalars (cannot be scratch-allocated)
    LT(0)  LT(1)  LT(2)  LT(3)  LT(4)  LT(5)  LT(6)  LT(7)
    LT(8)  LT(9)  LT(10) LT(11) LT(12) LT(13) LT(14) LT(15)
    LT(16) LT(17) LT(18) LT(19) LT(20) LT(21) LT(22) LT(23)
    LT(24) LT(25) LT(26) LT(27) LT(28) LT(29) LT(30) LT(31)
    LT(32) LT(33) LT(34) LT(35) LT(36) LT(37) LT(38) LT(39)
    LT(40) LT(41) LT(42) LT(43) LT(44) LT(45) LT(46) LT(47)

    if (act) s[j] = startT[j] + fb[j];   // init: start + emit[0]
    __builtin_amdgcn_wave_barrier();
    asm volatile("s_waitcnt lgkmcnt(0)");
    __builtin_amdgcn_wave_barrier();

    // emit prefetch pipeline, depth 2
    float emit_c = fb[(size_t)1 * TT + jj];   // for t=1
    float emit_n = fb[(size_t)2 * TT + jj];   // for t=2
    float snew = 0.f;

    for (int t = 1; t < SEQ; ++t) {
        const float emit = emit_c;
        const int tp = t + 2 < SEQ ? t + 2 : SEQ - 1;
        const float emit_f = fb[(size_t)tp * TT + jj];   // prefetch t+2

        // 12 named LDS quads (uniform address -> broadcast, conflict-free)
        const float4 sq0 = ls[0];  const float4 sq1 = ls[1];
        const float4 sq2 = ls[2];  const float4 sq3 = ls[3];
        const float4 sq4 = ls[4];  const float4 sq5 = ls[5];
        const float4 sq6 = ls[6];  const float4 sq7 = ls[7];
        const float4 sq8 = ls[8];  const float4 sq9 = ls[9];
        const float4 sq10 = ls[10]; const float4 sq11 = ls[11];

        // level 0: 48 candidates -> 24 (keep-left ties everywhere)
        P0(0, sq0, x, y, 0, 1)    P0(1, sq0, z, w, 2, 3)
        P0(2, sq1, x, y, 4, 5)    P0(3, sq1, z, w, 6, 7)
        P0(4, sq2, x, y, 8, 9)    P0(5, sq2, z, w, 10, 11)
        P0(6, sq3, x, y, 12, 13)  P0(7, sq3, z, w, 14, 15)
        P0(8, sq4, x, y, 16, 17)  P0(9, sq4, z, w, 18, 19)
        P0(10, sq5, x, y, 20, 21) P0(11, sq5, z, w, 22, 23)
        P0(12, sq6, x, y, 24, 25) P0(13, sq6, z, w, 26, 27)
        P0(14, sq7, x, y, 28, 29) P0(15, sq7, z, w, 30, 31)
        P0(16, sq8, x, y, 32, 33) P0(17, sq8, z, w, 34, 35)
        P0(18, sq9, x, y, 36, 37) P0(19, sq9, z, w, 38, 39)
        P0(20, sq10, x, y, 40, 41) P0(21, sq10, z, w, 42, 43)
        P0(22, sq11, x, y, 44, 45) P0(23, sq11, z, w, 46, 47)

        // level 1: 24 -> 12
        CMB(u0, y0, v0, x0, v1, x1)     CMB(u1, y1, v2, x2, v3, x3)
        CMB(u2, y2, v4, x4, v5, x5)     CMB(u3, y3, v6, x6, v7, x7)
        CMB(u4, y4, v8, x8, v9, x9)     CMB(u5, y5, v10, x10, v11, x11)
        CMB(u6, y6, v12, x12, v13, x13) CMB(u7, y7, v14, x14, v15, x15)
        CMB(u8, y8, v16, x16, v17, x17) CMB(u9, y9, v18, x18, v19, x19)
        CMB(u10, y10, v20, x20, v21, x21) CMB(u11, y11, v22, x22, v23, x23)

        // level 2: 12 -> 6
        CMB(p0, q0, u0, y0, u1, y1)   CMB(p1, q1, u2, y2, u3, y3)
        CMB(p2, q2, u4, y4, u5, y5)   CMB(p3, q3, u6, y6, u7, y7)
        CMB(p4, q4, u8, y8, u9, y9)   CMB(p5, q5, u10, y10, u11, y11)

        // level 3: 6 -> 3
        CMB(r0, z0, p0, q0, p1, q1)
        CMB(r1, z1, p2, q2, p3, q3)
        CMB(r2, z2, p4, q4, p5, q5)

        // level 4: 3 -> 1 (keep-left: (0..31) vs (32..47))
        CMB(m0, n0, r0, z0, r1, z1)
        CMB(mf, nf, m0, n0, r2, z2)

        if (act) bp[((size_t)(t - 1) * BATCH + b) * TT + j] = (unsigned char)nf;

        snew = mf + emit;
        emit_c = emit_n;            // rotate prefetch pipeline
        emit_n = emit_f;
        __builtin_amdgcn_wave_barrier();   // keep reads above the write
        if (act) s[j] = snew;
        __builtin_amdgcn_wave_barrier();
        asm volatile("s_waitcnt lgkmcnt(0)");   // write visible before next reads
        __builtin_amdgcn_wave_barrier();
    }

    // final: + end_transitions, argmax over tags (first occurrence)
    fin[threadIdx.x] = act ? (snew + endT[j]) : -1e30f;
    __syncthreads();   // once; cost irrelevant
    if (threadIdx.x == 0) {
        float bb = fin[0]; int bt = 0;
        for (int i = 1; i < TT; ++i)
            if (fin[i] > bb) { bb = fin[i]; bt = i; }
        best_out[b] = bb;
        last_tag[b] = bt;
    }
}

// ------------- Backtrack phase 1: compose per-chunk pointer maps ------------
__global__ __launch_bounds__(64) void vit_compose(
    const unsigned char* __restrict__ bp, unsigned char* __restrict__ maps)
{
    const int b = blockIdx.x, c = blockIdx.y;
    const int k_lo = c * CHUNK;
    const int len = min(CHUNK, BPLEN - k_lo);
    __shared__ __align__(16) unsigned char rows[CHUNK * TT];  // 6 KiB
    unsigned int* rows32 = reinterpret_cast<unsigned int*>(rows);

    const int ndw = len * (TT / 4);      // 12 dwords per 48B row
    for (int f = threadIdx.x; f < ndw; f += 64) {
        int row = f / 12, dwi = f % 12;
        const unsigned int* src = reinterpret_cast<const unsigned int*>(
            bp + ((size_t)(k_lo + row) * BATCH + b) * TT);
        rows32[row * 12 + dwi] = src[dwi];
    }
    __syncthreads();

    int j = threadIdx.x;
    if (j < TT) {
        int cur = j;                     // hypothesis: tag at chunk end == j
        for (int t = len - 1; t >= 0; --t) cur = rows[t * TT + cur];
        maps[((size_t)b * NCH + c) * TT + j] = (unsigned char)cur;
    }
}

// ------------- Backtrack phase 2: boundary tags via 16 chunk maps -----------
__global__ void vit_boundary(
    const unsigned char* __restrict__ maps, const int* __restrict__ last_tag,
    unsigned char* __restrict__ btag, void* __restrict__ out_tags, int i64mode)
{
    int b = threadIdx.x;                 // launched with 512 threads, 1 block
    if (b >= BATCH) return;
    int cur = last_tag[b];
    if (i64mode) ((long long*)out_tags)[(size_t)b * SEQ + (SEQ - 1)] = cur;
    else         ((float*)out_tags)[(size_t)b * SEQ + (SEQ - 1)] = (float)cur;
    for (int c = NCH - 1; c >= 0; --c) {
        btag[b * NCH + c] = (unsigned char)cur;     // tag at chunk c's end
        cur = maps[((size_t)b * NCH + c) * TT + cur];
    }
}

// ------------- Backtrack phase 3: emit tags within each chunk ---------------
__global__ __launch_bounds__(64) void vit_emit(
    const unsigned char* __restrict__ bp, const unsigned char* __restrict__ btag,
    void* __restrict__ out_tags, int i64mode)
{
    const int b = blockIdx.x, c = blockIdx.y;
    const int k_lo = c * CHUNK;
    const int len = min(CHUNK, BPLEN - k_lo);
    __shared__ __align__(16) unsigned char rows[CHUNK * TT];
    __shared__ unsigned char path[CHUNK];
    unsigned int* rows32 = reinterpret_cast<unsigned int*>(rows);

    const int ndw = len * (TT / 4);
    for (int f = threadIdx.x; f < ndw; f += 64) {
        int row = f / 12, dwi = f % 12;
        const unsigned int* src = reinterpret_cast<const unsigned int*>(
            bp + ((size_t)(k_lo + row) * BATCH + b) * TT);
        rows32[row * 12 + dwi] = src[dwi];
    }
    __syncthreads();

    if (threadIdx.x == 0) {
        int cur = btag[b * NCH + c];     // tag at position k_lo + len
        for (int t = len - 1; t >= 0; --t) {
            cur = rows[t * TT + cur];
            path[t] = (unsigned char)cur;   // tag at position k_lo + t
        }
    }
    __syncthreads();

    for (int k = threadIdx.x; k < len; k += 64) {
        int tag = path[k];
        if (i64mode) ((long long*)out_tags)[(size_t)b * SEQ + k_lo + k] = tag;
        else         ((float*)out_tags)[(size_t)b * SEQ + k_lo + k] = (float)tag;
    }
}

extern "C" void kernel_launch(void* const* d_in, const int* in_sizes, int n_in,
                              void* d_out, int out_size, void* d_ws, size_t ws_size,
                              hipStream_t stream) {
    const float* feats  = (const float*)d_in[0];
    const float* startT = (const float*)d_in[1];
    const float* endT   = (const float*)d_in[2];
    const float* trans  = (const float*)d_in[3];

    // workspace layout (bytes)
    unsigned char* ws   = (unsigned char*)d_ws;
    unsigned char* bp   = ws;                                 // 2047*512*48 = 50,307,072
    unsigned char* maps = ws + (size_t)BPLEN * BATCH * TT;    // 512*16*48 = 393,216
    unsigned char* btag = maps + (size_t)BATCH * NCH * TT;    // 512*16 = 8,192
    int* last_tag       = (int*)(btag + (size_t)BATCH * NCH); // 512*4

    float* best_out = (float*)d_out;
    void* out_tags  = (void*)((float*)d_out + BATCH);  // after 512 score floats
    const int i64mode = (out_size == BATCH + 2 * BATCH * SEQ) ? 1 : 0;

    vit_fwd<<<BATCH, 64, 0, stream>>>(feats, startT, endT, trans,
                                      bp, last_tag, best_out);
    vit_compose<<<dim3(BATCH, NCH), 64, 0, stream>>>(bp, maps);
    vit_boundary<<<1, BATCH, 0, stream>>>(maps, last_tag, btag, out_tags, i64mode);
    vit_emit<<<dim3(BATCH, NCH), 64, 0, stream>>>(bp, btag, out_tags, i64mode);
}

// Round 8
// 1844.624 us; speedup vs baseline: 4.1581x; 1.0304x over previous
//
#include <hip/hip_runtime.h>
#include <hip/hip_bf16.h>

// Batched Viterbi decode (torchcrf CRF.decode), B=512, S=2048, T=48.
// Outputs: best_score f32[512], tags [512][2048] (f32 or i64 depending on harness).
//
// R7 post-mortem: named scalars removed scratch round-trips (7270->1640us) but
// VGPR stayed 48 => allocator REMATERIALIZES the trans loads inside the loop
// (~48 L1 loads/step on the critical path, ~1500 cy/step of non-VALU time).
// Fix: pin each tc value through opaque inline asm ("+v") -- its def becomes
// the asm result, so the load cannot be rematerialized and the value must stay
// in a VGPR for the whole kernel.

#define BATCH 512
#define SEQ   2048
#define TT    48
#define BPLEN (SEQ - 1)      // 2047 backpointer rows
#define CHUNK 128
#define NCH   16             // ceil(2047/128)

// combine (va,xa),(vb,xb) -> (vc,xc), keep-left on ties (first-occurrence argmax)
#define CMB(vc, xc, va, xa, vb, xb) \
    const bool g_##vc = (vb) > (va); \
    const float vc = g_##vc ? (vb) : (va); \
    const int xc = g_##vc ? (xb) : (xa);

// level-0 pair from LDS quad sq, fields f0/f1, tag indices e0<e1
#define P0(k, sq, f0, f1, e0, e1) \
    const float a_##k = sq.f0 + tc##e0; \
    const float b_##k = sq.f1 + tc##e1; \
    const bool g0_##k = b_##k > a_##k; \
    const float v##k = g0_##k ? b_##k : a_##k; \
    const int x##k = g0_##k ? e1 : e0;

// load + PIN: value's def is the opaque asm, so the load can't be remat'd
#define LT(i) float tc##i = trans[i * TT + jj]; \
    asm volatile("" : "+v"(tc##i));

// ---------------- Forward DP: one wave per batch, lane j = cur tag ----------
__global__ __launch_bounds__(64, 1) void vit_fwd(
    const float* __restrict__ feats, const float* __restrict__ startT,
    const float* __restrict__ endT, const float* __restrict__ trans,
    unsigned char* __restrict__ bp, int* __restrict__ last_tag,
    float* __restrict__ best_out)
{
    const int b = blockIdx.x;
    const int j = threadIdx.x;
    const int jj = j < TT ? j : TT - 1;      // clamped lane for loads
    const bool act = j < TT;
    __shared__ __align__(16) float s[TT];
    __shared__ float fin[64];
    const float4* ls = reinterpret_cast<const float4*>(s);

    const float* fb = feats + (size_t)b * (SEQ * TT);

    // 48 named + PINNED transition-column scalars (register-resident, no remat)
    LT(0)  LT(1)  LT(2)  LT(3)  LT(4)  LT(5)  LT(6)  LT(7)
    LT(8)  LT(9)  LT(10) LT(11) LT(12) LT(13) LT(14) LT(15)
    LT(16) LT(17) LT(18) LT(19) LT(20) LT(21) LT(22) LT(23)
    LT(24) LT(25) LT(26) LT(27) LT(28) LT(29) LT(30) LT(31)
    LT(32) LT(33) LT(34) LT(35) LT(36) LT(37) LT(38) LT(39)
    LT(40) LT(41) LT(42) LT(43) LT(44) LT(45) LT(46) LT(47)

    if (act) s[j] = startT[j] + fb[j];   // init: start + emit[0]
    __builtin_amdgcn_wave_barrier();
    asm volatile("s_waitcnt lgkmcnt(0)");
    __builtin_amdgcn_wave_barrier();

    // emit prefetch pipeline, depth 2
    float emit_c = fb[(size_t)1 * TT + jj];   // for t=1
    float emit_n = fb[(size_t)2 * TT + jj];   // for t=2
    float snew = 0.f;

    for (int t = 1; t < SEQ; ++t) {
        const float emit = emit_c;
        const int tp = t + 2 < SEQ ? t + 2 : SEQ - 1;
        const float emit_f = fb[(size_t)tp * TT + jj];   // prefetch t+2

        // 12 named LDS quads (uniform address -> broadcast, conflict-free)
        const float4 sq0 = ls[0];  const float4 sq1 = ls[1];
        const float4 sq2 = ls[2];  const float4 sq3 = ls[3];
        const float4 sq4 = ls[4];  const float4 sq5 = ls[5];
        const float4 sq6 = ls[6];  const float4 sq7 = ls[7];
        const float4 sq8 = ls[8];  const float4 sq9 = ls[9];
        const float4 sq10 = ls[10]; const float4 sq11 = ls[11];

        // level 0: 48 candidates -> 24 (keep-left ties everywhere)
        P0(0, sq0, x, y, 0, 1)    P0(1, sq0, z, w, 2, 3)
        P0(2, sq1, x, y, 4, 5)    P0(3, sq1, z, w, 6, 7)
        P0(4, sq2, x, y, 8, 9)    P0(5, sq2, z, w, 10, 11)
        P0(6, sq3, x, y, 12, 13)  P0(7, sq3, z, w, 14, 15)
        P0(8, sq4, x, y, 16, 17)  P0(9, sq4, z, w, 18, 19)
        P0(10, sq5, x, y, 20, 21) P0(11, sq5, z, w, 22, 23)
        P0(12, sq6, x, y, 24, 25) P0(13, sq6, z, w, 26, 27)
        P0(14, sq7, x, y, 28, 29) P0(15, sq7, z, w, 30, 31)
        P0(16, sq8, x, y, 32, 33) P0(17, sq8, z, w, 34, 35)
        P0(18, sq9, x, y, 36, 37) P0(19, sq9, z, w, 38, 39)
        P0(20, sq10, x, y, 40, 41) P0(21, sq10, z, w, 42, 43)
        P0(22, sq11, x, y, 44, 45) P0(23, sq11, z, w, 46, 47)

        // level 1: 24 -> 12
        CMB(u0, y0, v0, x0, v1, x1)     CMB(u1, y1, v2, x2, v3, x3)
        CMB(u2, y2, v4, x4, v5, x5)     CMB(u3, y3, v6, x6, v7, x7)
        CMB(u4, y4, v8, x8, v9, x9)     CMB(u5, y5, v10, x10, v11, x11)
        CMB(u6, y6, v12, x12, v13, x13) CMB(u7, y7, v14, x14, v15, x15)
        CMB(u8, y8, v16, x16, v17, x17) CMB(u9, y9, v18, x18, v19, x19)
        CMB(u10, y10, v20, x20, v21, x21) CMB(u11, y11, v22, x22, v23, x23)

        // level 2: 12 -> 6
        CMB(p0, q0, u0, y0, u1, y1)   CMB(p1, q1, u2, y2, u3, y3)
        CMB(p2, q2, u4, y4, u5, y5)   CMB(p3, q3, u6, y6, u7, y7)
        CMB(p4, q4, u8, y8, u9, y9)   CMB(p5, q5, u10, y10, u11, y11)

        // level 3: 6 -> 3
        CMB(r0, z0, p0, q0, p1, q1)
        CMB(r1, z1, p2, q2, p3, q3)
        CMB(r2, z2, p4, q4, p5, q5)

        // level 4: 3 -> 1 (keep-left: (0..31) vs (32..47))
        CMB(m0, n0, r0, z0, r1, z1)
        CMB(mf, nf, m0, n0, r2, z2)

        if (act) bp[((size_t)(t - 1) * BATCH + b) * TT + j] = (unsigned char)nf;

        snew = mf + emit;
        emit_c = emit_n;            // rotate prefetch pipeline
        emit_n = emit_f;
        __builtin_amdgcn_wave_barrier();   // keep reads above the write
        if (act) s[j] = snew;
        __builtin_amdgcn_wave_barrier();
        asm volatile("s_waitcnt lgkmcnt(0)");   // write visible before next reads
        __builtin_amdgcn_wave_barrier();
    }

    // final: + end_transitions, argmax over tags (first occurrence)
    fin[threadIdx.x] = act ? (snew + endT[j]) : -1e30f;
    __syncthreads();   // once; cost irrelevant
    if (threadIdx.x == 0) {
        float bb = fin[0]; int bt = 0;
        for (int i = 1; i < TT; ++i)
            if (fin[i] > bb) { bb = fin[i]; bt = i; }
        best_out[b] = bb;
        last_tag[b] = bt;
    }
}

// ------------- Backtrack phase 1: compose per-chunk pointer maps ------------
__global__ __launch_bounds__(64) void vit_compose(
    const unsigned char* __restrict__ bp, unsigned char* __restrict__ maps)
{
    const int b = blockIdx.x, c = blockIdx.y;
    const int k_lo = c * CHUNK;
    const int len = min(CHUNK, BPLEN - k_lo);
    __shared__ __align__(16) unsigned char rows[CHUNK * TT];  // 6 KiB
    unsigned int* rows32 = reinterpret_cast<unsigned int*>(rows);

    const int ndw = len * (TT / 4);      // 12 dwords per 48B row
    for (int f = threadIdx.x; f < ndw; f += 64) {
        int row = f / 12, dwi = f % 12;
        const unsigned int* src = reinterpret_cast<const unsigned int*>(
            bp + ((size_t)(k_lo + row) * BATCH + b) * TT);
        rows32[row * 12 + dwi] = src[dwi];
    }
    __syncthreads();

    int j = threadIdx.x;
    if (j < TT) {
        int cur = j;                     // hypothesis: tag at chunk end == j
        for (int t = len - 1; t >= 0; --t) cur = rows[t * TT + cur];
        maps[((size_t)b * NCH + c) * TT + j] = (unsigned char)cur;
    }
}

// ------------- Backtrack phase 2: boundary tags via 16 chunk maps -----------
__global__ void vit_boundary(
    const unsigned char* __restrict__ maps, const int* __restrict__ last_tag,
    unsigned char* __restrict__ btag, void* __restrict__ out_tags, int i64mode)
{
    int b = threadIdx.x;                 // launched with 512 threads, 1 block
    if (b >= BATCH) return;
    int cur = last_tag[b];
    if (i64mode) ((long long*)out_tags)[(size_t)b * SEQ + (SEQ - 1)] = cur;
    else         ((float*)out_tags)[(size_t)b * SEQ + (SEQ - 1)] = (float)cur;
    for (int c = NCH - 1; c >= 0; --c) {
        btag[b * NCH + c] = (unsigned char)cur;     // tag at chunk c's end
        cur = maps[((size_t)b * NCH + c) * TT + cur];
    }
}

// ------------- Backtrack phase 3: emit tags within each chunk ---------------
__global__ __launch_bounds__(64) void vit_emit(
    const unsigned char* __restrict__ bp, const unsigned char* __restrict__ btag,
    void* __restrict__ out_tags, int i64mode)
{
    const int b = blockIdx.x, c = blockIdx.y;
    const int k_lo = c * CHUNK;
    const int len = min(CHUNK, BPLEN - k_lo);
    __shared__ __align__(16) unsigned char rows[CHUNK * TT];
    __shared__ unsigned char path[CHUNK];
    unsigned int* rows32 = reinterpret_cast<unsigned int*>(rows);

    const int ndw = len * (TT / 4);
    for (int f = threadIdx.x; f < ndw; f += 64) {
        int row = f / 12, dwi = f % 12;
        const unsigned int* src = reinterpret_cast<const unsigned int*>(
            bp + ((size_t)(k_lo + row) * BATCH + b) * TT);
        rows32[row * 12 + dwi] = src[dwi];
    }
    __syncthreads();

    if (threadIdx.x == 0) {
        int cur = btag[b * NCH + c];     // tag at position k_lo + len
        for (int t = len - 1; t >= 0; --t) {
            cur = rows[t * TT + cur];
            path[t] = (unsigned char)cur;   // tag at position k_lo + t
        }
    }
    __syncthreads();

    for (int k = threadIdx.x; k < len; k += 64) {
        int tag = path[k];
        if (i64mode) ((long long*)out_tags)[(size_t)b * SEQ + k_lo + k] = tag;
        else         ((float*)out_tags)[(size_t)b * SEQ + k_lo + k] = (float)tag;
    }
}

extern "C" void kernel_launch(void* const* d_in, const int* in_sizes, int n_in,
                              void* d_out, int out_size, void* d_ws, size_t ws_size,
                              hipStream_t stream) {
    const float* feats  = (const float*)d_in[0];
    const float* startT = (const float*)d_in[1];
    const float* endT   = (const float*)d_in[2];
    const float* trans  = (const float*)d_in[3];

    // workspace layout (bytes)
    unsigned char* ws   = (unsigned char*)d_ws;
    unsigned char* bp   = ws;                                 // 2047*512*48 = 50,307,072
    unsigned char* maps = ws + (size_t)BPLEN * BATCH * TT;    // 512*16*48 = 393,216
    unsigned char* btag = maps + (size_t)BATCH * NCH * TT;    // 512*16 = 8,192
    int* last_tag       = (int*)(btag + (size_t)BATCH * NCH); // 512*4

    float* best_out = (float*)d_out;
    void* out_tags  = (void*)((float*)d_out + BATCH);  // after 512 score floats
    const int i64mode = (out_size == BATCH + 2 * BATCH * SEQ) ? 1 : 0;

    vit_fwd<<<BATCH, 64, 0, stream>>>(feats, startT, endT, trans,
                                      bp, last_tag, best_out);
    vit_compose<<<dim3(BATCH, NCH), 64, 0, stream>>>(bp, maps);
    vit_boundary<<<1, BATCH, 0, stream>>>(maps, last_tag, btag, out_tags, i64mode);
    vit_emit<<<dim3(BATCH, NCH), 64, 0, stream>>>(bp, btag, out_tags, i64mode);
}

// Round 9
// 1697.503 us; speedup vs baseline: 4.5185x; 1.0867x over previous
//
#include <hip/hip_runtime.h>
#include <hip/hip_bf16.h>

// Batched Viterbi decode (torchcrf CRF.decode), B=512, S=2048, T=48.
// Outputs: best_score f32[512], tags [512][2048] (f32 or i64 depending).
//
// R8 post-mortem: VGPR pinned at 48 across all variants => compiler schedules
// LDS/L1 reads just-in-time, serializing ~12 x ~150cy latencies per DP step
// (1870 cy/step, VALU issue only ~410 cy). Fix: the 48 prev scores are wave-
// uniform, so broadcast them with v_readlane -> SGPRs. Hot loop is now pure
// register/VALU: no LDS, no waitcnt, no barriers, ~250 VALU insts/step.

#define BATCH 512
#define SEQ   2048
#define TT    48
#define BPLEN (SEQ - 1)      // 2047 backpointer rows
#define CHUNK 128
#define NCH   16             // ceil(2047/128)

// combine (va,xa),(vb,xb) -> (vc,xc), keep-left on ties (first-occurrence argmax)
#define CMB(vc, xc, va, xa, vb, xb) \
    const bool g_##vc = (vb) > (va); \
    const float vc = g_##vc ? (vb) : (va); \
    const int xc = g_##vc ? (xb) : (xa);

// readlane broadcast of prev-score lane i -> uniform (SGPR) value
#define RL(i) const float sv##i = \
    __int_as_float(__builtin_amdgcn_readlane(__float_as_int(snew), i));

// level-0 pair: candidates for prev tags e0,e1 (e0 < e1), keep-left on tie
#define P0(k, e0, e1) \
    const float a_##k = sv##e0 + tc##e0; \
    const float b_##k = sv##e1 + tc##e1; \
    const bool g0_##k = b_##k > a_##k; \
    const float v##k = g0_##k ? b_##k : a_##k; \
    const int x##k = g0_##k ? e1 : e0;

// load + pin transition scalar (pin is free; discourages remat)
#define LT(i) float tc##i = trans[i * TT + jj]; \
    asm volatile("" : "+v"(tc##i));

// ---------------- Forward DP: one wave per batch, lane j = cur tag ----------
__global__ __launch_bounds__(64, 1) void vit_fwd(
    const float* __restrict__ feats, const float* __restrict__ startT,
    const float* __restrict__ endT, const float* __restrict__ trans,
    unsigned char* __restrict__ bp, int* __restrict__ last_tag,
    float* __restrict__ best_out)
{
    const int b = blockIdx.x;
    const int j = threadIdx.x;
    const int jj = j < TT ? j : TT - 1;      // clamped lane for loads
    const bool act = j < TT;
    __shared__ float fin[64];

    const float* fb = feats + (size_t)b * (SEQ * TT);

    // 48 named transition-column scalars
    LT(0)  LT(1)  LT(2)  LT(3)  LT(4)  LT(5)  LT(6)  LT(7)
    LT(8)  LT(9)  LT(10) LT(11) LT(12) LT(13) LT(14) LT(15)
    LT(16) LT(17) LT(18) LT(19) LT(20) LT(21) LT(22) LT(23)
    LT(24) LT(25) LT(26) LT(27) LT(28) LT(29) LT(30) LT(31)
    LT(32) LT(33) LT(34) LT(35) LT(36) LT(37) LT(38) LT(39)
    LT(40) LT(41) LT(42) LT(43) LT(44) LT(45) LT(46) LT(47)

    // init: start + emit[0]; lives in a register from here on
    float snew = startT[jj] + fb[jj];

    // emit prefetch pipeline, depth 2
    float emit_c = fb[(size_t)1 * TT + jj];   // for t=1
    float emit_n = fb[(size_t)2 * TT + jj];   // for t=2

    for (int t = 1; t < SEQ; ++t) {
        const float emit = emit_c;
        const int tp = t + 2 < SEQ ? t + 2 : SEQ - 1;
        const float emit_f = fb[(size_t)tp * TT + jj];   // prefetch t+2

        // broadcast all 48 prev scores to SGPRs (no memory, no waits)
        RL(0)  RL(1)  RL(2)  RL(3)  RL(4)  RL(5)  RL(6)  RL(7)
        RL(8)  RL(9)  RL(10) RL(11) RL(12) RL(13) RL(14) RL(15)
        RL(16) RL(17) RL(18) RL(19) RL(20) RL(21) RL(22) RL(23)
        RL(24) RL(25) RL(26) RL(27) RL(28) RL(29) RL(30) RL(31)
        RL(32) RL(33) RL(34) RL(35) RL(36) RL(37) RL(38) RL(39)
        RL(40) RL(41) RL(42) RL(43) RL(44) RL(45) RL(46) RL(47)

        // level 0: 48 candidates -> 24 (keep-left ties everywhere)
        P0(0, 0, 1)    P0(1, 2, 3)    P0(2, 4, 5)    P0(3, 6, 7)
        P0(4, 8, 9)    P0(5, 10, 11)  P0(6, 12, 13)  P0(7, 14, 15)
        P0(8, 16, 17)  P0(9, 18, 19)  P0(10, 20, 21) P0(11, 22, 23)
        P0(12, 24, 25) P0(13, 26, 27) P0(14, 28, 29) P0(15, 30, 31)
        P0(16, 32, 33) P0(17, 34, 35) P0(18, 36, 37) P0(19, 38, 39)
        P0(20, 40, 41) P0(21, 42, 43) P0(22, 44, 45) P0(23, 46, 47)

        // level 1: 24 -> 12
        CMB(u0, y0, v0, x0, v1, x1)     CMB(u1, y1, v2, x2, v3, x3)
        CMB(u2, y2, v4, x4, v5, x5)     CMB(u3, y3, v6, x6, v7, x7)
        CMB(u4, y4, v8, x8, v9, x9)     CMB(u5, y5, v10, x10, v11, x11)
        CMB(u6, y6, v12, x12, v13, x13) CMB(u7, y7, v14, x14, v15, x15)
        CMB(u8, y8, v16, x16, v17, x17) CMB(u9, y9, v18, x18, v19, x19)
        CMB(u10, y10, v20, x20, v21, x21) CMB(u11, y11, v22, x22, v23, x23)

        // level 2: 12 -> 6
        CMB(p0, q0, u0, y0, u1, y1)   CMB(p1, q1, u2, y2, u3, y3)
        CMB(p2, q2, u4, y4, u5, y5)   CMB(p3, q3, u6, y6, u7, y7)
        CMB(p4, q4, u8, y8, u9, y9)   CMB(p5, q5, u10, y10, u11, y11)

        // level 3: 6 -> 3
        CMB(r0, z0, p0, q0, p1, q1)
        CMB(r1, z1, p2, q2, p3, q3)
        CMB(r2, z2, p4, q4, p5, q5)

        // level 4: 3 -> 1 (keep-left: (0..31) then (32..47))
        CMB(m0, n0, r0, z0, r1, z1)
        CMB(mf, nf, m0, n0, r2, z2)

        if (act) bp[((size_t)(t - 1) * BATCH + b) * TT + j] = (unsigned char)nf;

        snew = mf + emit;           // register recurrence; next iter readlanes it
        emit_c = emit_n;            // rotate prefetch pipeline
        emit_n = emit_f;
    }

    // final: + end_transitions, argmax over tags (first occurrence)
    fin[threadIdx.x] = act ? (snew + endT[j]) : -1e30f;
    __syncthreads();   // once; cost irrelevant
    if (threadIdx.x == 0) {
        float bb = fin[0]; int bt = 0;
        for (int i = 1; i < TT; ++i)
            if (fin[i] > bb) { bb = fin[i]; bt = i; }
        best_out[b] = bb;
        last_tag[b] = bt;
    }
}

// ------------- Backtrack phase 1: compose per-chunk pointer maps ------------
__global__ __launch_bounds__(64) void vit_compose(
    const unsigned char* __restrict__ bp, unsigned char* __restrict__ maps)
{
    const int b = blockIdx.x, c = blockIdx.y;
    const int k_lo = c * CHUNK;
    const int len = min(CHUNK, BPLEN - k_lo);
    __shared__ __align__(16) unsigned char rows[CHUNK * TT];  // 6 KiB
    unsigned int* rows32 = reinterpret_cast<unsigned int*>(rows);

    const int ndw = len * (TT / 4);      // 12 dwords per 48B row
    for (int f = threadIdx.x; f < ndw; f += 64) {
        int row = f / 12, dwi = f % 12;
        const unsigned int* src = reinterpret_cast<const unsigned int*>(
            bp + ((size_t)(k_lo + row) * BATCH + b) * TT);
        rows32[row * 12 + dwi] = src[dwi];
    }
    __syncthreads();

    int j = threadIdx.x;
    if (j < TT) {
        int cur = j;                     // hypothesis: tag at chunk end == j
        for (int t = len - 1; t >= 0; --t) cur = rows[t * TT + cur];
        maps[((size_t)b * NCH + c) * TT + j] = (unsigned char)cur;
    }
}

// ------------- Backtrack phase 2: boundary tags via 16 chunk maps -----------
__global__ void vit_boundary(
    const unsigned char* __restrict__ maps, const int* __restrict__ last_tag,
    unsigned char* __restrict__ btag, void* __restrict__ out_tags, int i64mode)
{
    int b = threadIdx.x;                 // launched with 512 threads, 1 block
    if (b >= BATCH) return;
    int cur = last_tag[b];
    if (i64mode) ((long long*)out_tags)[(size_t)b * SEQ + (SEQ - 1)] = cur;
    else         ((float*)out_tags)[(size_t)b * SEQ + (SEQ - 1)] = (float)cur;
    for (int c = NCH - 1; c >= 0; --c) {
        btag[b * NCH + c] = (unsigned char)cur;     // tag at chunk c's end
        cur = maps[((size_t)b * NCH + c) * TT + cur];
    }
}

// ------------- Backtrack phase 3: emit tags within each chunk ---------------
__global__ __launch_bounds__(64) void vit_emit(
    const unsigned char* __restrict__ bp, const unsigned char* __restrict__ btag,
    void* __restrict__ out_tags, int i64mode)
{
    const int b = blockIdx.x, c = blockIdx.y;
    const int k_lo = c * CHUNK;
    const int len = min(CHUNK, BPLEN - k_lo);
    __shared__ __align__(16) unsigned char rows[CHUNK * TT];
    __shared__ unsigned char path[CHUNK];
    unsigned int* rows32 = reinterpret_cast<unsigned int*>(rows);

    const int ndw = len * (TT / 4);
    for (int f = threadIdx.x; f < ndw; f += 64) {
        int row = f / 12, dwi = f % 12;
        const unsigned int* src = reinterpret_cast<const unsigned int*>(
            bp + ((size_t)(k_lo + row) * BATCH + b) * TT);
        rows32[row * 12 + dwi] = src[dwi];
    }
    __syncthreads();

    if (threadIdx.x == 0) {
        int cur = btag[b * NCH + c];     // tag at position k_lo + len
        for (int t = len - 1; t >= 0; --t) {
            cur = rows[t * TT + cur];
            path[t] = (unsigned char)cur;   // tag at position k_lo + t
        }
    }
    __syncthreads();

    for (int k = threadIdx.x; k < len; k += 64) {
        int tag = path[k];
        if (i64mode) ((long long*)out_tags)[(size_t)b * SEQ + k_lo + k] = tag;
        else         ((float*)out_tags)[(size_t)b * SEQ + k_lo + k] = (float)tag;
    }
}

extern "C" void kernel_launch(void* const* d_in, const int* in_sizes, int n_in,
                              void* d_out, int out_size, void* d_ws, size_t ws_size,
                              hipStream_t stream) {
    const float* feats  = (const float*)d_in[0];
    const float* startT = (const float*)d_in[1];
    const float* endT   = (const float*)d_in[2];
    const float* trans  = (const float*)d_in[3];

    // workspace layout (bytes)
    unsigned char* ws   = (unsigned char*)d_ws;
    unsigned char* bp   = ws;                                 // 2047*512*48 = 50,307,072
    unsigned char* maps = ws + (size_t)BPLEN * BATCH * TT;    // 512*16*48 = 393,216
    unsigned char* btag = maps + (size_t)BATCH * NCH * TT;    // 512*16 = 8,192
    int* last_tag       = (int*)(btag + (size_t)BATCH * NCH); // 512*4

    float* best_out = (float*)d_out;
    void* out_tags  = (void*)((float*)d_out + BATCH);  // after 512 score floats
    const int i64mode = (out_size == BATCH + 2 * BATCH * SEQ) ? 1 : 0;

    vit_fwd<<<BATCH, 64, 0, stream>>>(feats, startT, endT, trans,
                                      bp, last_tag, best_out);
    vit_compose<<<dim3(BATCH, NCH), 64, 0, stream>>>(bp, maps);
    vit_boundary<<<1, BATCH, 0, stream>>>(maps, last_tag, btag, out_tags, i64mode);
    vit_emit<<<dim3(BATCH, NCH), 64, 0, stream>>>(bp, btag, out_tags, i64mode);
}